// Round 1
// baseline (284.130 us; speedup 1.0000x reference)
//
#include <hip/hip_runtime.h>

// Closed-form solution of the cascading-sink-cache scan.
//
// The reference's control flow (writeA/writeB/slotD, stored, start, active) is
// identical for all sequences and independent of scores; only the slotD
// compare (cur_s >= old_s) is data-dependent, and it never feeds back into the
// schedule. Unrolling the deterministic schedule, each final cache slot holds
// the winner of a depth<=3 score tournament over a closed-form token set:
//   cascade 0: FIFO of last 512 tokens.
//   cascade 1: winners of consecutive token pairs (post-warm push+compare).
//   cascade 2: pair winners / 4-token tournaments of cascade-1 evictees.
//   cascade 3: raw warm tokens + pair winners of cascade-2 evictees.
// Token t (0-based cascade token) lives at input row t+4 (rows 0..3 = sinks,
// which are not part of the output). W(a,b): b (the "cur"/later item) wins ties.

__device__ __forceinline__ int wpair(const float* __restrict__ sc, int a, int b) {
    return (sc[b] >= sc[a]) ? b : a;
}

__device__ __forceinline__ int final_token(const float* __restrict__ sc, int s) {
    const int g = s >> 9;    // cascade index
    const int c = s & 511;   // slot within cascade
    if (g == 0) {
        // pure FIFO: last 512 tokens
        return c + ((c <= 507) ? 3584 : 3072);
    } else if (g == 1) {
        // final push n (mod-512 rule, Pmax=2555); Q1[n] = W(2n-1532, 2n-1531)
        const int n = (c <= 507) ? (2048 + c) : (1536 + c);
        const int a = 2 * n - 1532;
        return wpair(sc, a, a + 1);
    } else if (g == 2) {
        // final push r (Pmax=1531); Q2[r] = W(Q1[2r-1020], Q1[2r-1019])
        const int r = (c <= 507) ? (1024 + c) : (512 + c);
        if (r <= 1275) {
            // both Q1 operands are raw tokens (index <= 1531)
            const int a = 2 * r - 1020;
            return wpair(sc, a, a + 1);
        } else {
            // both Q1 operands are pair winners: 4-token tournament
            const int n0 = 2 * r - 1020;        // 1532..2042
            const int a0 = 2 * n0 - 1532;       // 1532..2552
            const int t1 = wpair(sc, a0, a0 + 1);
            const int t2 = wpair(sc, a0 + 2, a0 + 3);  // t2 is the slotD "cur"
            return wpair(sc, t1, t2);
        }
    } else {
        // cascade 3 (Pmax=764): slots 253..508 keep warm tokens c;
        // slots 0..252 hold pushes u=512+c: W(Q2[2u-509], Q2[2u-508]) over raw
        // tokens, last push (u=764) unpaired; slots 509..511 hold Q3[c].
        if (c <= 251) { const int a = 515 + 2 * c; return wpair(sc, a, a + 1); }
        if (c == 252) return 1019;               // Q2[1019], never compared
        if (c <= 508) return c;                  // warm writeA, never evicted
        const int a = 2 * c - 509;               // c=509..511: (509,510),(511,512),(513,514)
        return wpair(sc, a, a + 1);
    }
}

__global__ __launch_bounds__(256) void cascade_gather(
        const float4* __restrict__ k, const float4* __restrict__ v,
        const float* __restrict__ score, float4* __restrict__ out) {
    const int seq = blockIdx.y;            // 0..63  (n*32 + h)
    const int rg  = threadIdx.x >> 5;      // row group 0..7
    const int q   = threadIdx.x & 31;      // float4 lane within row
    const int s   = (blockIdx.x << 3) + rg;        // slot 0..2047

    const float* sc = score + seq * 4096 + 4;      // index by cascade token t
    const int t = final_token(sc, s);

    const size_t src_row = (size_t)(seq * 4096 + t + 4) * 32;  // 128 floats = 32 float4
    const size_t dst_row = (size_t)(seq * 2048 + s) * 64;      // 256 floats = 64 float4

    out[dst_row + q]      = k[src_row + q];   // cache_k -> out[..., 0:128]
    out[dst_row + 32 + q] = v[src_row + q];   // cache_v -> out[..., 128:256]
}

extern "C" void kernel_launch(void* const* d_in, const int* in_sizes, int n_in,
                              void* d_out, int out_size, void* d_ws, size_t ws_size,
                              hipStream_t stream) {
    const float4* k  = (const float4*)d_in[0];
    const float4* v  = (const float4*)d_in[1];
    const float*  sc = (const float*)d_in[2];
    float4* out = (float4*)d_out;

    dim3 grid(256, 64);   // 256 blocks x 8 slots = 2048 slots; y = 64 sequences
    cascade_gather<<<grid, 256, 0, stream>>>(k, v, sc, out);
}